// Round 5
// baseline (222.600 us; speedup 1.0000x reference)
//
#include <hip/hip_runtime.h>
#include <hip/hip_bf16.h>

// GPT-2 attention block. Inputs/outputs fp32; internal bf16 MFMA, fp32 accum.
// B=4, S=1024, D=1024, H=16, hd=64.
//
// R5: attention restructured as barrier-free wave-per-16-q-rows. K/V MFMA
//     fragments load directly global->VGPR (b128, fully coalesced: 16 rows x
//     64B per instruction); P round-trip through wave-private LDS (lgkmcnt
//     only). Latency hidden by ~16 independent waves/CU instead of barriers.

typedef __bf16 bf16x8 __attribute__((ext_vector_type(8)));
typedef float f32x4 __attribute__((ext_vector_type(4)));

__device__ __forceinline__ void load_lds16(const void* g, void* l) {
  __builtin_amdgcn_global_load_lds(
      (const __attribute__((address_space(1))) void*)g,
      (__attribute__((address_space(3))) void*)l, 16, 0, 0);
}

// ---------------- convert fp32 -> bf16 ----------------
__global__ __launch_bounds__(256) void f32_to_bf16(
    const float* __restrict__ in, __bf16* __restrict__ out, int n) {
  int i = (blockIdx.x * 256 + threadIdx.x) * 4;
  if (i + 3 < n) {
    float4 v = *(const float4*)(in + i);
    out[i + 0] = (__bf16)v.x;
    out[i + 1] = (__bf16)v.y;
    out[i + 2] = (__bf16)v.z;
    out[i + 3] = (__bf16)v.w;
  }
}

// ---------------- convert+transpose: WT[n*K+k] = (bf16)W[k*N+n] ----------------
__global__ __launch_bounds__(256) void transpose_f32_bf16(
    const float* __restrict__ W, __bf16* __restrict__ WT, int K, int N) {
  __shared__ __bf16 tile[32][33];
  int n0 = blockIdx.x * 32, k0 = blockIdx.y * 32;
  int tx = threadIdx.x, ty = threadIdx.y;  // block (32,8)
#pragma unroll
  for (int j = 0; j < 32; j += 8)
    tile[ty + j][tx] = (__bf16)W[(size_t)(k0 + ty + j) * N + n0 + tx];
  __syncthreads();
#pragma unroll
  for (int j = 0; j < 32; j += 8)
    WT[(size_t)(n0 + ty + j) * K + k0 + tx] = tile[tx][ty + j];
}

// ---------------- V transpose: VT[bh][d][s] from QKV ----------------
__global__ __launch_bounds__(256) void transpose_v(
    const __bf16* __restrict__ qkv, __bf16* __restrict__ VT) {
  const int lane = threadIdx.x & 63, wave = threadIdx.x >> 6;
  const int bh = blockIdx.x >> 4;
  const int kb = (blockIdx.x & 15) * 64;
  const int b = bh >> 4, h = bh & 15;
  const __bf16* src =
      qkv + ((size_t)b * 1024 + kb + lane) * 3072 + 2048 + h * 64 + wave * 16;
  bf16x8 v0 = *(const bf16x8*)src;
  bf16x8 v1 = *(const bf16x8*)(src + 8);
  __bf16* dst = VT + ((size_t)bh * 64 + wave * 16) * 1024 + kb + lane;
#pragma unroll
  for (int i = 0; i < 8; ++i) {
    dst[(size_t)i * 1024] = v0[i];
    dst[(size_t)(i + 8) * 1024] = v1[i];
  }
}

// ---------------- GEMM (m97 structure): C = A @ BT^T + bias ----------------
template <typename OutT>
__global__ __launch_bounds__(256) void gemm_bt_bias(
    const __bf16* __restrict__ A, const __bf16* __restrict__ BT,
    const float* __restrict__ bias, OutT* __restrict__ C, int M, int N, int K) {
  __shared__ __bf16 sA[128 * 32];
  __shared__ __bf16 sB[128 * 32];

  const int tid = threadIdx.x;
  const int lane = tid & 63;
  const int wave = tid >> 6;
  const int waveM = wave >> 1, waveN = wave & 1;
  const int quad = lane >> 4;
  const int l16 = lane & 15;
  const int rowBase = blockIdx.y * 128;
  const int colBase = blockIdx.x * 128;

  const int rIn = lane >> 2;
  const int sIn = lane & 3;
  const int gc = sIn ^ (rIn & 3) ^ ((rIn >> 2) & 3);
  const int readSlot = quad ^ (l16 & 3) ^ ((l16 >> 2) & 3);

  f32x4 acc[4][4] = {};

  for (int k0 = 0; k0 < K; k0 += 32) {
    __syncthreads();
#pragma unroll
    for (int j = 0; j < 2; ++j) {
      const int rb = wave * 32 + j * 16;
      load_lds16(&A[(size_t)(rowBase + rb + rIn) * K + k0 + gc * 8], &sA[rb * 32]);
      load_lds16(&BT[(size_t)(colBase + rb + rIn) * K + k0 + gc * 8], &sB[rb * 32]);
    }
    __syncthreads();

    bf16x8 af[4], bfr[4];
#pragma unroll
    for (int mt = 0; mt < 4; ++mt)
      af[mt] = *(const bf16x8*)(&sA[(waveM * 64 + mt * 16 + l16) * 32 + readSlot * 8]);
#pragma unroll
    for (int nt = 0; nt < 4; ++nt)
      bfr[nt] = *(const bf16x8*)(&sB[(waveN * 64 + nt * 16 + l16) * 32 + readSlot * 8]);
#pragma unroll
    for (int mt = 0; mt < 4; ++mt)
#pragma unroll
      for (int nt = 0; nt < 4; ++nt)
        acc[mt][nt] = __builtin_amdgcn_mfma_f32_16x16x32_bf16(
            af[mt], bfr[nt], acc[mt][nt], 0, 0, 0);
  }

#pragma unroll
  for (int mt = 0; mt < 4; ++mt) {
    int row = rowBase + waveM * 64 + mt * 16 + quad * 4;
#pragma unroll
    for (int nt = 0; nt < 4; ++nt) {
      int col = colBase + waveN * 64 + nt * 16 + l16;
      float bv = bias[col];
#pragma unroll
      for (int r = 0; r < 4; ++r)
        C[(size_t)(row + r) * N + col] = (OutT)(acc[mt][nt][r] + bv);
    }
  }
}

// ---------------- flash attention: barrier-free, wave-per-16-q-rows ----------------
// Block = 1 wave = 16 query rows of one (b,h). K-tiles of 64 keys; K and V
// fragments read directly from global (L2/L3-resident working set). P goes
// through a wave-private LDS buffer (C-layout -> A-layout); no __syncthreads.
__global__ __launch_bounds__(64) void attn_mfma(
    const __bf16* __restrict__ qkv, const __bf16* __restrict__ VT,
    __bf16* __restrict__ Aout) {
  __shared__ __bf16 pw[16 * 64];  // 2 KB, wave-private P buffer

  const int lane = threadIdx.x;
  const int quad = lane >> 4;
  const int l16 = lane & 15;

  const int bh = blockIdx.x & 63;         // consecutive blocks: same qw, all bh
  const int qw = 63 - (blockIdx.x >> 6);  // heaviest q-tiles dispatch first
  const int b = bh >> 4, h = bh & 15;
  const int qb = qw * 16;

  const size_t rowS = 3072;
  const __bf16* Qb = qkv + (size_t)b * 1024 * rowS + h * 64;
  const __bf16* Kb = Qb + 1024;
  const __bf16* VTb = VT + (size_t)bh * 64 * 1024;

  // Q A-fragments: A[m=l16][k=quad*8+j] and k+32
  bf16x8 qA0, qA1;
  {
    const __bf16* qr = Qb + (size_t)(qb + l16) * rowS + quad * 8;
    qA0 = *(const bf16x8*)qr;
    qA1 = *(const bf16x8*)(qr + 32);
  }

  f32x4 Oacc[4] = {};  // [d-subtile]: row q=quad*4+r, col d=nt*16+l16
  float m_run[4], l_run[4];
#pragma unroll
  for (int r = 0; r < 4; ++r) { m_run[r] = -3.0e38f; l_run[r] = 0.f; }

  const int swq = l16 & 7;
  const int ktiles = (qb >> 6) + 1;

  for (int kt = 0; kt < ktiles; ++kt) {
    const int kb = kt * 64;

    // ---- K B-fragments, direct global b128 (16 rows x 64B per instruction)
    bf16x8 kB0[4], kB1[4];
#pragma unroll
    for (int n = 0; n < 4; ++n) {
      const __bf16* kr = Kb + (size_t)(kb + n * 16 + l16) * rowS + quad * 8;
      kB0[n] = *(const bf16x8*)kr;
      kB1[n] = *(const bf16x8*)(kr + 32);
    }

    // ---- QK^T: 4 key-subtiles x (k=0..31, 32..63)
    float sc[4][4];
#pragma unroll
    for (int n = 0; n < 4; ++n) {
      f32x4 c = {};
      c = __builtin_amdgcn_mfma_f32_16x16x32_bf16(qA0, kB0[n], c, 0, 0, 0);
      c = __builtin_amdgcn_mfma_f32_16x16x32_bf16(qA1, kB1[n], c, 0, 0, 0);
#pragma unroll
      for (int r = 0; r < 4; ++r) sc[n][r] = c[r] * 0.125f;
    }

    // ---- V B-fragments (issued before softmax so fetch overlaps it)
    bf16x8 vB0[4], vB1[4];
#pragma unroll
    for (int nt = 0; nt < 4; ++nt) {
      const __bf16* vr = VTb + (size_t)(nt * 16 + l16) * 1024 + kb + quad * 8;
      vB0[nt] = *(const bf16x8*)vr;
      vB1[nt] = *(const bf16x8*)(vr + 32);
    }

    // ---- causal mask (only the tile containing the diagonal)
    if (kt == ktiles - 1) {
#pragma unroll
      for (int n = 0; n < 4; ++n) {
        const int kg = kb + n * 16 + l16;
#pragma unroll
        for (int r = 0; r < 4; ++r)
          if (kg > qb + quad * 4 + r) sc[n][r] = -10000.0f;
      }
    }

    // ---- online softmax (q-row = 16 lanes of a quad)
    float alpha[4];
#pragma unroll
    for (int r = 0; r < 4; ++r) {
      float tmax = fmaxf(fmaxf(sc[0][r], sc[1][r]), fmaxf(sc[2][r], sc[3][r]));
      tmax = fmaxf(tmax, __shfl_xor(tmax, 1));
      tmax = fmaxf(tmax, __shfl_xor(tmax, 2));
      tmax = fmaxf(tmax, __shfl_xor(tmax, 4));
      tmax = fmaxf(tmax, __shfl_xor(tmax, 8));
      const float newm = fmaxf(m_run[r], tmax);
      alpha[r] = __expf(m_run[r] - newm);
      m_run[r] = newm;
      float ps = 0.f;
#pragma unroll
      for (int n = 0; n < 4; ++n) {
        float p = __expf(sc[n][r] - newm);
        sc[n][r] = p;
        ps += p;
      }
      ps += __shfl_xor(ps, 1);
      ps += __shfl_xor(ps, 2);
      ps += __shfl_xor(ps, 4);
      ps += __shfl_xor(ps, 8);
      l_run[r] = l_run[r] * alpha[r] + ps;
    }

    // ---- P: C-layout regs -> wave-private LDS (swizzled) -> A-fragments
    {
      const int kb8 = l16 >> 3, lo = l16 & 7;
#pragma unroll
      for (int n = 0; n < 4; ++n) {
        const int chunk = n * 2 + kb8;
#pragma unroll
        for (int r = 0; r < 4; ++r) {
          const int q = quad * 4 + r;
          pw[q * 64 + ((chunk ^ (q & 7)) << 3) + lo] = (__bf16)sc[n][r];
        }
      }
    }

    // ---- rescale O, then PV (wave-local lgkmcnt ordering only, no barrier)
#pragma unroll
    for (int nt = 0; nt < 4; ++nt)
#pragma unroll
      for (int r = 0; r < 4; ++r) Oacc[nt][r] *= alpha[r];

    bf16x8 pA0 = *(const bf16x8*)(&pw[l16 * 64 + ((quad ^ swq) << 3)]);
    bf16x8 pA1 = *(const bf16x8*)(&pw[l16 * 64 + (((quad + 4) ^ swq) << 3)]);
#pragma unroll
    for (int nt = 0; nt < 4; ++nt) {
      Oacc[nt] = __builtin_amdgcn_mfma_f32_16x16x32_bf16(pA0, vB0[nt], Oacc[nt], 0, 0, 0);
      Oacc[nt] = __builtin_amdgcn_mfma_f32_16x16x32_bf16(pA1, vB1[nt], Oacc[nt], 0, 0, 0);
    }
  }

  // ---- epilogue
  float inv[4];
#pragma unroll
  for (int r = 0; r < 4; ++r) inv[r] = 1.0f / l_run[r];
#pragma unroll
  for (int nt = 0; nt < 4; ++nt) {
#pragma unroll
    for (int r = 0; r < 4; ++r) {
      const int q = qb + quad * 4 + r;
      Aout[((size_t)b * 1024 + q) * 1024 + h * 64 + nt * 16 + l16] =
          (__bf16)(Oacc[nt][r] * inv[r]);
    }
  }
}

// ---------------- launch ----------------
extern "C" void kernel_launch(void* const* d_in, const int* in_sizes, int n_in,
                              void* d_out, int out_size, void* d_ws,
                              size_t ws_size, hipStream_t stream) {
  const float* x      = (const float*)d_in[0];
  const float* w_attn = (const float*)d_in[1];
  const float* b_attn = (const float*)d_in[2];
  const float* w_proj = (const float*)d_in[3];
  const float* b_proj = (const float*)d_in[4];
  float* out = (float*)d_out;

  char* ws = (char*)d_ws;
  __bf16* WT_attn = (__bf16*)(ws);                  //  6 MB
  __bf16* WT_proj = (__bf16*)(ws + 6291456);        //  2 MB
  __bf16* Xb      = (__bf16*)(ws + 8388608);        //  8 MB (reused as VT)
  __bf16* QKV     = (__bf16*)(ws + 16777216);       // 24 MB
  __bf16* Aattn   = (__bf16*)(ws + 41943040);       //  8 MB (total 48 MB)
  __bf16* VT      = Xb;  // x-as-bf16 dead after GEMM1; reuse for V^T

  transpose_f32_bf16<<<dim3(96, 32), dim3(32, 8), 0, stream>>>(
      w_attn, WT_attn, 1024, 3072);
  transpose_f32_bf16<<<dim3(32, 32), dim3(32, 8), 0, stream>>>(
      w_proj, WT_proj, 1024, 1024);
  f32_to_bf16<<<4096, 256, 0, stream>>>(x, Xb, 4096 * 1024);
  gemm_bt_bias<__bf16><<<dim3(24, 32), 256, 0, stream>>>(
      Xb, WT_attn, b_attn, QKV, 4096, 3072, 1024);
  transpose_v<<<1024, 256, 0, stream>>>(QKV, VT);
  attn_mfma<<<4096, 64, 0, stream>>>(QKV, VT, Aattn);
  gemm_bt_bias<float><<<dim3(8, 32), 256, 0, stream>>>(
      Aattn, WT_proj, b_proj, out, 4096, 1024, 1024);
}